// Round 2
// baseline (637.050 us; speedup 1.0000x reference)
//
#include <hip/hip_runtime.h>
#include <hip/hip_bf16.h>
#include <cmath>

#define DD 128

__device__ __forceinline__ float sigm(float x) { return 1.0f / (1.0f + expf(-x)); }

__global__ void k_root(const float* __restrict__ mu_min, const float* __restrict__ mu_max,
                       const float* __restrict__ braw_min, const float* __restrict__ braw_max,
                       float* __restrict__ out) {
    int i = blockIdx.x * blockDim.x + threadIdx.x;
    if (i >= 64 * DD) return;
    out[i] = mu_min[i];
    out[8192 + i] = mu_max[i];
    out[16384 + i] = sigm(braw_min[i]) + 1e-6f;
    out[24576 + i] = sigm(braw_max[i]) + 1e-6f;
}

// One block = 128 threads (one per d), TC children per block.
// Pass A: stage w (gumbel hard sign test) into LDS.
// Pass B: dot over P -> b_min/b_max.
// Pass C: streaming logsumexp over P -> mu_min_i/mu_max_i.
template<int P, int TC>
__global__ __launch_bounds__(128)
void k_level(const float* __restrict__ logits, const float* __restrict__ u,
             const float* __restrict__ pmu_min, const float* __restrict__ pmu_max,
             const float* __restrict__ pb_min, const float* __restrict__ pb_max,
             float* __restrict__ o_mu_min, float* __restrict__ o_mu_max,
             float* __restrict__ o_b_min, float* __restrict__ o_b_max) {
    __shared__ float wsh[TC * P];
    const int c0 = blockIdx.x * TC;
    const int d = threadIdx.x;

    // stage hard gumbel-sigmoid weights: w = 1[(logits + g) > 0]
    for (int i = threadIdx.x; i < TC * P; i += 128) {
        int j = i / P;
        int p = i - j * P;
        int idx = (c0 + j) * P + p;
        float uu = u[idx] + 1e-10f;
        float g = -logf(-logf(uu) + 1e-10f);
        wsh[i] = (logits[idx] + g > 0.0f) ? 1.0f : 0.0f;
    }
    __syncthreads();

    // pass B: weighted beta average
    float wsum[TC], dmn[TC], dmx[TC];
    #pragma unroll
    for (int j = 0; j < TC; ++j) { wsum[j] = 0.f; dmn[j] = 0.f; dmx[j] = 0.f; }

    for (int p = 0; p < P; ++p) {
        float bm = pb_min[p * DD + d];
        float bx = pb_max[p * DD + d];
        #pragma unroll
        for (int j = 0; j < TC; ++j) {
            float wv = wsh[j * P + p];
            wsum[j] += wv;
            dmn[j] = fmaf(wv, bm, dmn[j]);
            dmx[j] = fmaf(wv, bx, dmx[j]);
        }
    }

    float bmin[TC], bmax[TC], rmin[TC], rmax[TC];
    #pragma unroll
    for (int j = 0; j < TC; ++j) {
        float wsv = wsum[j] + 1e-10f;
        bmin[j] = dmn[j] / wsv;
        bmax[j] = dmx[j] / wsv;
        rmin[j] = 1.0f / bmin[j];
        rmax[j] = 1.0f / bmax[j];
    }

    // pass C: streaming logsumexp (online max + rescale), both sides
    float mn_m[TC], mn_s[TC], mx_m[TC], mx_s[TC];
    #pragma unroll
    for (int j = 0; j < TC; ++j) {
        mn_m[j] = -INFINITY; mn_s[j] = 0.f;
        mx_m[j] = -INFINITY; mx_s[j] = 0.f;
    }

    for (int p = 0; p < P; ++p) {
        float mm = pmu_min[p * DD + d];
        float mxv = pmu_max[p * DD + d];
        #pragma unroll
        for (int j = 0; j < TC; ++j) {
            // log(w + 1e-10) in f32 is exactly 0.0f (w=1) or log(1e-10) (w=0)
            float lw = (wsh[j * P + p] != 0.0f) ? 0.0f : -23.025850929940457f;
            float a1 = fmaf(mm, rmin[j], lw);
            float n1 = fmaxf(mn_m[j], a1);
            mn_s[j] = mn_s[j] * expf(mn_m[j] - n1) + expf(a1 - n1);
            mn_m[j] = n1;
            float a2 = fmaf(-mxv, rmax[j], lw);
            float n2 = fmaxf(mx_m[j], a2);
            mx_s[j] = mx_s[j] * expf(mx_m[j] - n2) + expf(a2 - n2);
            mx_m[j] = n2;
        }
    }

    #pragma unroll
    for (int j = 0; j < TC; ++j) {
        int idx = (c0 + j) * DD + d;
        o_mu_min[idx] = bmin[j] * (mn_m[j] + logf(mn_s[j]));
        o_mu_max[idx] = -bmax[j] * (mx_m[j] + logf(mx_s[j]));
        o_b_min[idx]  = bmin[j];
        o_b_max[idx]  = bmax[j];
    }
}

extern "C" void kernel_launch(void* const* d_in, const int* in_sizes, int n_in,
                              void* d_out, int out_size, void* d_ws, size_t ws_size,
                              hipStream_t stream) {
    const float* mu_min0  = (const float*)d_in[0];
    const float* mu_max0  = (const float*)d_in[1];
    const float* braw_min = (const float*)d_in[2];
    const float* braw_max = (const float*)d_in[3];
    const float* adj0     = (const float*)d_in[4];   // (512, 64)
    const float* adj1     = (const float*)d_in[5];   // (2048, 512)
    const float* u0       = (const float*)d_in[6];   // (1, 512, 64)
    const float* u1       = (const float*)d_in[7];   // (1, 2048, 512)
    float* out = (float*)d_out;

    // out offsets (elements, f32):
    // 0:mu_min0  8192:mu_max0  16384:bmin0  24576:bmax0
    // 32768:mu_min1  98304:mu_max1  163840:b_min1  229376:b_max1   (each 65536)
    // 294912:mu_min2 557056:mu_max2 819200:b_min2 1081344:b_max2   (each 262144)

    k_root<<<dim3(32), dim3(256), 0, stream>>>(mu_min0, mu_max0, braw_min, braw_max, out);

    k_level<64, 4><<<dim3(512 / 4), dim3(128), 0, stream>>>(
        adj0, u0, mu_min0, mu_max0, out + 16384, out + 24576,
        out + 32768, out + 98304, out + 163840, out + 229376);

    k_level<512, 4><<<dim3(2048 / 4), dim3(128), 0, stream>>>(
        adj1, u1, out + 32768, out + 98304, out + 163840, out + 229376,
        out + 294912, out + 557056, out + 819200, out + 1081344);
}

// Round 3
// 207.510 us; speedup vs baseline: 3.0700x; 3.0700x over previous
//
#include <hip/hip_runtime.h>
#include <cmath>

#define DD 128

__device__ __forceinline__ float sigm(float x) { return 1.0f / (1.0f + __expf(-x)); }

__global__ void k_root(const float* __restrict__ mu_min, const float* __restrict__ mu_max,
                       const float* __restrict__ braw_min, const float* __restrict__ braw_max,
                       float* __restrict__ out) {
    int i = blockIdx.x * blockDim.x + threadIdx.x;
    if (i >= 64 * DD) return;
    out[i] = mu_min[i];
    out[8192 + i] = mu_max[i];
    out[16384 + i] = sigm(braw_min[i]) + 1e-6f;
    out[24576 + i] = sigm(braw_max[i]) + 1e-6f;
}

// Per-d column max over parents: cm_min[d] = max_p mu_min[p,d], cm_neg[d] = max_p(-mu_max[p,d]).
// Independent of c and of w — hoisted out of the main kernel so the LSE needs no max pass.
template<int P, int G>
__global__ void k_colmax(const float* __restrict__ mu_min, const float* __restrict__ mu_max,
                         float* __restrict__ cm_min, float* __restrict__ cm_neg) {
    __shared__ float r1[G][DD], r2[G][DD];
    int tid = threadIdx.x;
    int g = tid >> 7, d = tid & (DD - 1);
    float m1 = -INFINITY, m2 = -INFINITY;
    for (int p = g; p < P; p += G) {
        m1 = fmaxf(m1, mu_min[p * DD + d]);
        m2 = fmaxf(m2, -mu_max[p * DD + d]);
    }
    r1[g][d] = m1; r2[g][d] = m2;
    __syncthreads();
    if (tid < DD) {
        float a = r1[0][d], b = r2[0][d];
        #pragma unroll
        for (int g2 = 1; g2 < G; ++g2) { a = fmaxf(a, r1[g2][d]); b = fmaxf(b, r2[g2][d]); }
        cm_min[d] = a;
        cm_neg[d] = b;
    }
}

// One block = 128 threads (one per d), TC children per block.
// Pass A: stage wf = w + 1e-10 (gumbel hard sign test) into LDS.
// Pass B: dot over P -> b_min/b_max (reads betas only).
// Pass C: single-pass sum of wf*exp(x - M) with hoisted column max M (no serial rescale chain).
template<int P, int TC>
__global__ __launch_bounds__(128)
void k_level(const float* __restrict__ logits, const float* __restrict__ u,
             const float* __restrict__ pb_min, const float* __restrict__ pb_max,
             const float* __restrict__ pmu_min, const float* __restrict__ pmu_max,
             const float* __restrict__ cm_min, const float* __restrict__ cm_neg,
             float* __restrict__ o_mu_min, float* __restrict__ o_mu_max,
             float* __restrict__ o_b_min, float* __restrict__ o_b_max) {
    __shared__ float wsh[TC * P];
    const int c0 = blockIdx.x * TC;
    const int d = threadIdx.x;

    // pass A: wf = (logits + g > 0) ? 1 : 1e-10  (== exp(log(w + 1e-10)) exactly)
    for (int i = threadIdx.x; i < TC * P; i += 128) {
        int j = i / P;
        int p = i - j * P;
        int idx = (c0 + j) * P + p;
        float uu = u[idx] + 1e-10f;
        float g = -__logf(-__logf(uu) + 1e-10f);
        wsh[i] = (logits[idx] + g > 0.0f) ? 1.0f : 1e-10f;
    }
    __syncthreads();

    // pass B: weighted beta average
    float wsum[TC], dmn[TC], dmx[TC];
    #pragma unroll
    for (int j = 0; j < TC; ++j) { wsum[j] = 0.f; dmn[j] = 0.f; dmx[j] = 0.f; }

    #pragma unroll 4
    for (int p = 0; p < P; ++p) {
        float bm = pb_min[p * DD + d];
        float bx = pb_max[p * DD + d];
        #pragma unroll
        for (int j = 0; j < TC; ++j) {
            float wv = wsh[j * P + p];
            wsum[j] += wv;
            dmn[j] = fmaf(wv, bm, dmn[j]);
            dmx[j] = fmaf(wv, bx, dmx[j]);
        }
    }

    const float Mmm = cm_min[d];   // max_p mu_min[p,d]
    const float Mng = cm_neg[d];   // max_p -mu_max[p,d]

    float bmin[TC], bmax[TC], rmin[TC], nrmax[TC], negM1[TC], negM2[TC];
    #pragma unroll
    for (int j = 0; j < TC; ++j) {
        float wsv = wsum[j] + 1e-10f;
        bmin[j] = dmn[j] / wsv;
        bmax[j] = dmx[j] / wsv;
        rmin[j] = 1.0f / bmin[j];
        nrmax[j] = -1.0f / bmax[j];
        negM1[j] = -rmin[j] * Mmm;     // exp arg: mm*rmin - rmin*Mmm <= 0
        negM2[j] = nrmax[j] * Mng;     // exp arg: -mx*rmax - rmax*Mng <= 0
    }

    // pass C: s = sum_p wf_p * exp(x_p - M)
    float s1[TC], s2[TC];
    #pragma unroll
    for (int j = 0; j < TC; ++j) { s1[j] = 0.f; s2[j] = 0.f; }

    #pragma unroll 4
    for (int p = 0; p < P; ++p) {
        float mm = pmu_min[p * DD + d];
        float mx = pmu_max[p * DD + d];
        #pragma unroll
        for (int j = 0; j < TC; ++j) {
            float wv = wsh[j * P + p];
            float e1 = __expf(fmaf(mm, rmin[j], negM1[j]));
            s1[j] = fmaf(wv, e1, s1[j]);
            float e2 = __expf(fmaf(mx, nrmax[j], negM2[j]));
            s2[j] = fmaf(wv, e2, s2[j]);
        }
    }

    #pragma unroll
    for (int j = 0; j < TC; ++j) {
        int idx = (c0 + j) * DD + d;
        float lse1 = fmaf(rmin[j], Mmm, __logf(s1[j]));     // M'1 + log s1
        float lse2 = fmaf(-nrmax[j], Mng, __logf(s2[j]));   // M'2 + log s2
        o_mu_min[idx] = bmin[j] * lse1;
        o_mu_max[idx] = -bmax[j] * lse2;
        o_b_min[idx]  = bmin[j];
        o_b_max[idx]  = bmax[j];
    }
}

extern "C" void kernel_launch(void* const* d_in, const int* in_sizes, int n_in,
                              void* d_out, int out_size, void* d_ws, size_t ws_size,
                              hipStream_t stream) {
    const float* mu_min0  = (const float*)d_in[0];
    const float* mu_max0  = (const float*)d_in[1];
    const float* braw_min = (const float*)d_in[2];
    const float* braw_max = (const float*)d_in[3];
    const float* adj0     = (const float*)d_in[4];   // (512, 64)
    const float* adj1     = (const float*)d_in[5];   // (2048, 512)
    const float* u0       = (const float*)d_in[6];   // (1, 512, 64)
    const float* u1       = (const float*)d_in[7];   // (1, 2048, 512)
    float* out = (float*)d_out;
    float* ws = (float*)d_ws;

    // out offsets (elements, f32):
    // 0:mu_min0  8192:mu_max0  16384:bmin0  24576:bmax0
    // 32768:mu_min1  98304:mu_max1  163840:b_min1  229376:b_max1   (each 65536)
    // 294912:mu_min2 557056:mu_max2 819200:b_min2 1081344:b_max2   (each 262144)

    float* cm0_min = ws;
    float* cm0_neg = ws + 128;
    float* cm1_min = ws + 256;
    float* cm1_neg = ws + 384;

    k_root<<<dim3(32), dim3(256), 0, stream>>>(mu_min0, mu_max0, braw_min, braw_max, out);

    k_colmax<64, 2><<<dim3(1), dim3(256), 0, stream>>>(mu_min0, mu_max0, cm0_min, cm0_neg);

    k_level<64, 1><<<dim3(512), dim3(128), 0, stream>>>(
        adj0, u0, out + 16384, out + 24576, mu_min0, mu_max0, cm0_min, cm0_neg,
        out + 32768, out + 98304, out + 163840, out + 229376);

    k_colmax<512, 8><<<dim3(1), dim3(1024), 0, stream>>>(out + 32768, out + 98304, cm1_min, cm1_neg);

    k_level<512, 2><<<dim3(1024), dim3(128), 0, stream>>>(
        adj1, u1, out + 163840, out + 229376, out + 32768, out + 98304, cm1_min, cm1_neg,
        out + 294912, out + 557056, out + 819200, out + 1081344);
}

// Round 4
// 183.041 us; speedup vs baseline: 3.4804x; 1.1337x over previous
//
#include <hip/hip_runtime.h>
#include <cmath>

#define DD 128

__device__ __forceinline__ float sigm(float x) { return 1.0f / (1.0f + __expf(-x)); }

// Level-0 passthrough + fused column-max over level-0 parents (block 0 only).
__global__ void k_root(const float* __restrict__ mu_min, const float* __restrict__ mu_max,
                       const float* __restrict__ braw_min, const float* __restrict__ braw_max,
                       float* __restrict__ out,
                       float* __restrict__ cm_min, float* __restrict__ cm_neg) {
    int i = blockIdx.x * 256 + threadIdx.x;   // 32 blocks x 256 = 8192
    out[i] = mu_min[i];
    out[8192 + i] = mu_max[i];
    out[16384 + i] = sigm(braw_min[i]) + 1e-6f;
    out[24576 + i] = sigm(braw_max[i]) + 1e-6f;
    if (blockIdx.x == 0) {
        __shared__ float r1[2][DD], r2[2][DD];
        int g = threadIdx.x >> 7, d = threadIdx.x & (DD - 1);
        float m1 = -INFINITY, m2 = -INFINITY;
        for (int p = g; p < 64; p += 2) {
            m1 = fmaxf(m1, mu_min[p * DD + d]);
            m2 = fmaxf(m2, -mu_max[p * DD + d]);
        }
        r1[g][d] = m1; r2[g][d] = m2;
        __syncthreads();
        if (threadIdx.x < DD) {
            cm_min[d] = fmaxf(r1[0][d], r1[1][d]);
            cm_neg[d] = fmaxf(r2[0][d], r2[1][d]);
        }
    }
}

// Column max over level-1 parents (P=512): cm_min[d]=max_p mu_min, cm_neg[d]=max_p(-mu_max)
template<int P, int G>
__global__ void k_colmax(const float* __restrict__ mu_min, const float* __restrict__ mu_max,
                         float* __restrict__ cm_min, float* __restrict__ cm_neg) {
    __shared__ float r1[G][DD], r2[G][DD];
    int tid = threadIdx.x;
    int g = tid >> 7, d = tid & (DD - 1);
    float m1 = -INFINITY, m2 = -INFINITY;
    for (int p = g; p < P; p += G) {
        m1 = fmaxf(m1, mu_min[p * DD + d]);
        m2 = fmaxf(m2, -mu_max[p * DD + d]);
    }
    r1[g][d] = m1; r2[g][d] = m2;
    __syncthreads();
    if (tid < DD) {
        float a = r1[0][d], b = r2[0][d];
        #pragma unroll
        for (int g2 = 1; g2 < G; ++g2) { a = fmaxf(a, r1[g2][d]); b = fmaxf(b, r2[g2][d]); }
        cm_min[d] = a;
        cm_neg[d] = b;
    }
}

// Level-1: 128 threads (one per d), TC children per block, float4 LDS weight reads.
template<int P, int TC>
__global__ __launch_bounds__(128)
void k_level(const float* __restrict__ logits, const float* __restrict__ u,
             const float* __restrict__ pb_min, const float* __restrict__ pb_max,
             const float* __restrict__ pmu_min, const float* __restrict__ pmu_max,
             const float* __restrict__ cm_min, const float* __restrict__ cm_neg,
             float* __restrict__ o_mu_min, float* __restrict__ o_mu_max,
             float* __restrict__ o_b_min, float* __restrict__ o_b_max) {
    __shared__ __align__(16) float wsh[TC * P];
    const int c0 = blockIdx.x * TC;
    const int d = threadIdx.x;

    for (int i = threadIdx.x; i < TC * P; i += 128) {
        int j = i / P;
        int p = i - j * P;
        int idx = (c0 + j) * P + p;
        float uu = u[idx] + 1e-10f;
        float g = -__logf(-__logf(uu) + 1e-10f);
        wsh[i] = (logits[idx] + g > 0.0f) ? 1.0f : 1e-10f;
    }
    __syncthreads();

    float wsum[TC], dmn[TC], dmx[TC];
    #pragma unroll
    for (int j = 0; j < TC; ++j) { wsum[j] = 0.f; dmn[j] = 0.f; dmx[j] = 0.f; }

    for (int p = 0; p < P; p += 4) {
        float bm[4], bx[4];
        #pragma unroll
        for (int q = 0; q < 4; ++q) { bm[q] = pb_min[(p + q) * DD + d]; bx[q] = pb_max[(p + q) * DD + d]; }
        #pragma unroll
        for (int j = 0; j < TC; ++j) {
            float4 wv = *(const float4*)&wsh[j * P + p];
            wsum[j] += (wv.x + wv.y) + (wv.z + wv.w);
            dmn[j] = fmaf(wv.x, bm[0], fmaf(wv.y, bm[1], fmaf(wv.z, bm[2], fmaf(wv.w, bm[3], dmn[j]))));
            dmx[j] = fmaf(wv.x, bx[0], fmaf(wv.y, bx[1], fmaf(wv.z, bx[2], fmaf(wv.w, bx[3], dmx[j]))));
        }
    }

    const float Mmm = cm_min[d];
    const float Mng = cm_neg[d];
    float bmin[TC], bmax[TC], rmin[TC], nrmax[TC], negM1[TC], negM2[TC];
    #pragma unroll
    for (int j = 0; j < TC; ++j) {
        float wsv = wsum[j] + 1e-10f;
        bmin[j] = dmn[j] / wsv;
        bmax[j] = dmx[j] / wsv;
        rmin[j] = 1.0f / bmin[j];
        nrmax[j] = -1.0f / bmax[j];
        negM1[j] = -rmin[j] * Mmm;
        negM2[j] = nrmax[j] * Mng;
    }

    float s1[TC], s2[TC];
    #pragma unroll
    for (int j = 0; j < TC; ++j) { s1[j] = 0.f; s2[j] = 0.f; }

    for (int p = 0; p < P; p += 4) {
        float mm[4], mx[4];
        #pragma unroll
        for (int q = 0; q < 4; ++q) { mm[q] = pmu_min[(p + q) * DD + d]; mx[q] = pmu_max[(p + q) * DD + d]; }
        #pragma unroll
        for (int j = 0; j < TC; ++j) {
            float4 wv = *(const float4*)&wsh[j * P + p];
            s1[j] = fmaf(wv.x, __expf(fmaf(mm[0], rmin[j], negM1[j])), s1[j]);
            s1[j] = fmaf(wv.y, __expf(fmaf(mm[1], rmin[j], negM1[j])), s1[j]);
            s1[j] = fmaf(wv.z, __expf(fmaf(mm[2], rmin[j], negM1[j])), s1[j]);
            s1[j] = fmaf(wv.w, __expf(fmaf(mm[3], rmin[j], negM1[j])), s1[j]);
            s2[j] = fmaf(wv.x, __expf(fmaf(mx[0], nrmax[j], negM2[j])), s2[j]);
            s2[j] = fmaf(wv.y, __expf(fmaf(mx[1], nrmax[j], negM2[j])), s2[j]);
            s2[j] = fmaf(wv.z, __expf(fmaf(mx[2], nrmax[j], negM2[j])), s2[j]);
            s2[j] = fmaf(wv.w, __expf(fmaf(mx[3], nrmax[j], negM2[j])), s2[j]);
        }
    }

    #pragma unroll
    for (int j = 0; j < TC; ++j) {
        int idx = (c0 + j) * DD + d;
        o_mu_min[idx] = bmin[j] * fmaf(rmin[j], Mmm, __logf(s1[j]));
        o_mu_max[idx] = -bmax[j] * fmaf(-nrmax[j], Mng, __logf(s2[j]));
        o_b_min[idx]  = bmin[j];
        o_b_max[idx]  = bmax[j];
    }
}

// Level-2: 256 threads = two p-halves x 128 d-threads, TC children per block.
// Each half accumulates over P/2 parents; halves combine through LDS.
template<int P, int TC>
__global__ __launch_bounds__(256)
void k_level_split(const float* __restrict__ logits, const float* __restrict__ u,
                   const float* __restrict__ pb_min, const float* __restrict__ pb_max,
                   const float* __restrict__ pmu_min, const float* __restrict__ pmu_max,
                   const float* __restrict__ cm_min, const float* __restrict__ cm_neg,
                   float* __restrict__ o_mu_min, float* __restrict__ o_mu_max,
                   float* __restrict__ o_b_min, float* __restrict__ o_b_max) {
    constexpr int PH = P / 2;
    __shared__ __align__(16) float wsh[TC * P];
    __shared__ float redA[2][TC][DD];
    __shared__ float redB[2][TC][DD];
    __shared__ float wsumsh[2][TC];
    const int c0 = blockIdx.x * TC;
    const int h = threadIdx.x >> 7;          // p-half
    const int d = threadIdx.x & (DD - 1);
    const int p0 = h * PH;

    // pass A: wf = (logits + g > 0) ? 1 : 1e-10
    for (int i = threadIdx.x; i < TC * P; i += 256) {
        int j = i / P;
        int p = i - j * P;
        int idx = (c0 + j) * P + p;
        float uu = u[idx] + 1e-10f;
        float g = -__logf(-__logf(uu) + 1e-10f);
        wsh[i] = (logits[idx] + g > 0.0f) ? 1.0f : 1e-10f;
    }
    __syncthreads();

    // pass B: weighted beta sums over this half's p-range
    float wsum[TC], dmn[TC], dmx[TC];
    #pragma unroll
    for (int j = 0; j < TC; ++j) { wsum[j] = 0.f; dmn[j] = 0.f; dmx[j] = 0.f; }

    for (int pp = 0; pp < PH; pp += 4) {
        int p = p0 + pp;
        float bm[4], bx[4];
        #pragma unroll
        for (int q = 0; q < 4; ++q) { bm[q] = pb_min[(p + q) * DD + d]; bx[q] = pb_max[(p + q) * DD + d]; }
        #pragma unroll
        for (int j = 0; j < TC; ++j) {
            float4 wv = *(const float4*)&wsh[j * P + p];
            wsum[j] += (wv.x + wv.y) + (wv.z + wv.w);
            dmn[j] = fmaf(wv.x, bm[0], fmaf(wv.y, bm[1], fmaf(wv.z, bm[2], fmaf(wv.w, bm[3], dmn[j]))));
            dmx[j] = fmaf(wv.x, bx[0], fmaf(wv.y, bx[1], fmaf(wv.z, bx[2], fmaf(wv.w, bx[3], dmx[j]))));
        }
    }

    #pragma unroll
    for (int j = 0; j < TC; ++j) { redA[h][j][d] = dmn[j]; redB[h][j][d] = dmx[j]; }
    if (d == 0) {
        #pragma unroll
        for (int j = 0; j < TC; ++j) wsumsh[h][j] = wsum[j];
    }
    __syncthreads();

    const float Mmm = cm_min[d];
    const float Mng = cm_neg[d];
    float bmin[TC], bmax[TC], rmin[TC], nrmax[TC], negM1[TC], negM2[TC];
    #pragma unroll
    for (int j = 0; j < TC; ++j) {
        float wsv = (wsumsh[0][j] + wsumsh[1][j]) + 1e-10f;
        float Dmn = redA[0][j][d] + redA[1][j][d];
        float Dmx = redB[0][j][d] + redB[1][j][d];
        bmin[j] = Dmn / wsv;
        bmax[j] = Dmx / wsv;
        rmin[j] = 1.0f / bmin[j];
        nrmax[j] = -1.0f / bmax[j];
        negM1[j] = -rmin[j] * Mmm;
        negM2[j] = nrmax[j] * Mng;
    }
    __syncthreads();   // before reusing redA/redB

    // pass C: s = sum_p wf * exp(x - M) over this half's p-range
    float s1[TC], s2[TC];
    #pragma unroll
    for (int j = 0; j < TC; ++j) { s1[j] = 0.f; s2[j] = 0.f; }

    for (int pp = 0; pp < PH; pp += 4) {
        int p = p0 + pp;
        float mm[4], mx[4];
        #pragma unroll
        for (int q = 0; q < 4; ++q) { mm[q] = pmu_min[(p + q) * DD + d]; mx[q] = pmu_max[(p + q) * DD + d]; }
        #pragma unroll
        for (int j = 0; j < TC; ++j) {
            float4 wv = *(const float4*)&wsh[j * P + p];
            s1[j] = fmaf(wv.x, __expf(fmaf(mm[0], rmin[j], negM1[j])), s1[j]);
            s1[j] = fmaf(wv.y, __expf(fmaf(mm[1], rmin[j], negM1[j])), s1[j]);
            s1[j] = fmaf(wv.z, __expf(fmaf(mm[2], rmin[j], negM1[j])), s1[j]);
            s1[j] = fmaf(wv.w, __expf(fmaf(mm[3], rmin[j], negM1[j])), s1[j]);
            s2[j] = fmaf(wv.x, __expf(fmaf(mx[0], nrmax[j], negM2[j])), s2[j]);
            s2[j] = fmaf(wv.y, __expf(fmaf(mx[1], nrmax[j], negM2[j])), s2[j]);
            s2[j] = fmaf(wv.z, __expf(fmaf(mx[2], nrmax[j], negM2[j])), s2[j]);
            s2[j] = fmaf(wv.w, __expf(fmaf(mx[3], nrmax[j], negM2[j])), s2[j]);
        }
    }

    #pragma unroll
    for (int j = 0; j < TC; ++j) { redA[h][j][d] = s1[j]; redB[h][j][d] = s2[j]; }
    __syncthreads();

    if (h == 0) {
        #pragma unroll
        for (int j = 0; j < TC; ++j) {
            float S1 = redA[0][j][d] + redA[1][j][d];
            float S2 = redB[0][j][d] + redB[1][j][d];
            int idx = (c0 + j) * DD + d;
            o_mu_min[idx] = bmin[j] * fmaf(rmin[j], Mmm, __logf(S1));
            o_mu_max[idx] = -bmax[j] * fmaf(-nrmax[j], Mng, __logf(S2));
            o_b_min[idx]  = bmin[j];
            o_b_max[idx]  = bmax[j];
        }
    }
}

extern "C" void kernel_launch(void* const* d_in, const int* in_sizes, int n_in,
                              void* d_out, int out_size, void* d_ws, size_t ws_size,
                              hipStream_t stream) {
    const float* mu_min0  = (const float*)d_in[0];
    const float* mu_max0  = (const float*)d_in[1];
    const float* braw_min = (const float*)d_in[2];
    const float* braw_max = (const float*)d_in[3];
    const float* adj0     = (const float*)d_in[4];   // (512, 64)
    const float* adj1     = (const float*)d_in[5];   // (2048, 512)
    const float* u0       = (const float*)d_in[6];   // (1, 512, 64)
    const float* u1       = (const float*)d_in[7];   // (1, 2048, 512)
    float* out = (float*)d_out;
    float* ws = (float*)d_ws;

    float* cm0_min = ws;
    float* cm0_neg = ws + 128;
    float* cm1_min = ws + 256;
    float* cm1_neg = ws + 384;

    // out offsets (f32): 0:mu_min0 8192:mu_max0 16384:bmin0 24576:bmax0
    // 32768:mu_min1 98304:mu_max1 163840:b_min1 229376:b_max1 (each 65536)
    // 294912:mu_min2 557056:mu_max2 819200:b_min2 1081344:b_max2 (each 262144)

    k_root<<<dim3(32), dim3(256), 0, stream>>>(mu_min0, mu_max0, braw_min, braw_max,
                                               out, cm0_min, cm0_neg);

    k_level<64, 1><<<dim3(512), dim3(128), 0, stream>>>(
        adj0, u0, out + 16384, out + 24576, mu_min0, mu_max0, cm0_min, cm0_neg,
        out + 32768, out + 98304, out + 163840, out + 229376);

    k_colmax<512, 8><<<dim3(1), dim3(1024), 0, stream>>>(out + 32768, out + 98304, cm1_min, cm1_neg);

    k_level_split<512, 4><<<dim3(512), dim3(256), 0, stream>>>(
        adj1, u1, out + 163840, out + 229376, out + 32768, out + 98304, cm1_min, cm1_neg,
        out + 294912, out + 557056, out + 819200, out + 1081344);
}

// Round 5
// 159.511 us; speedup vs baseline: 3.9938x; 1.1475x over previous
//
#include <hip/hip_runtime.h>
#include <cmath>

#define DD 128

__device__ __forceinline__ float sigm(float x) { return 1.0f / (1.0f + __expf(-x)); }

// Level-0 passthrough.
__global__ void k_root(const float* __restrict__ mu_min, const float* __restrict__ mu_max,
                       const float* __restrict__ braw_min, const float* __restrict__ braw_max,
                       float* __restrict__ out) {
    int i = blockIdx.x * 256 + threadIdx.x;   // 32 blocks x 256 = 8192
    out[i] = mu_min[i];
    out[8192 + i] = mu_max[i];
    out[16384 + i] = sigm(braw_min[i]) + 1e-6f;
    out[24576 + i] = sigm(braw_max[i]) + 1e-6f;
}

// Column max over parents: block 0 -> cm_min[d] = max_p mu_min[p,d];
// block 1 -> cm_neg[d] = max_p(-mu_max[p,d]).  (c- and w-independent, hoisted.)
template<int P>
__global__ __launch_bounds__(1024)
void k_prep(const float* __restrict__ mu_min, const float* __restrict__ mu_max,
            float* __restrict__ cm_min, float* __restrict__ cm_neg) {
    __shared__ float red[8][DD];
    const int g = threadIdx.x >> 7, d = threadIdx.x & (DD - 1);
    float acc = -INFINITY;
    if (blockIdx.x == 0) {
        for (int p = g; p < P; p += 8) acc = fmaxf(acc, mu_min[p * DD + d]);
    } else {
        for (int p = g; p < P; p += 8) acc = fmaxf(acc, -mu_max[p * DD + d]);
    }
    red[g][d] = acc;
    __syncthreads();
    if (threadIdx.x < DD) {
        float a = red[0][d];
        #pragma unroll
        for (int g2 = 1; g2 < 8; ++g2) a = fmaxf(a, red[g2][d]);
        (blockIdx.x == 0 ? cm_min : cm_neg)[d] = a;
    }
}

// NT = TC*128 threads: child j = tid>>7, dim d = tid&127 (one thread per (child,d)).
// Pass A: gumbel hard sign test; wave-uniform ballot-compaction of present-parent
//         indices into plist[j][*] (w==1 exactly for present, 0 exactly for absent).
// Pass B: beta average over present list only (absent contribute exactly 0).
// Pass C: s = sum_present exp(x - M) with hoisted column max M (absent terms are
//         <=1e-10 relative -- dropped).
template<int P, int TC, int NT>
__global__ __launch_bounds__(NT)
void k_levelc(const float* __restrict__ logits, const float* __restrict__ u,
              const float* __restrict__ pb_min, const float* __restrict__ pb_max,
              const float* __restrict__ pmu_min, const float* __restrict__ pmu_max,
              const float* __restrict__ cm_min, const float* __restrict__ cm_neg,
              float* __restrict__ o_mu_min, float* __restrict__ o_mu_max,
              float* __restrict__ o_b_min, float* __restrict__ o_b_max) {
    __shared__ __align__(16) int plist[TC * P];
    __shared__ int npres[TC];
    const int tid = threadIdx.x;
    const int c0 = blockIdx.x * TC;
    const int lane = tid & 63;
    if (tid < TC) npres[tid] = 0;
    __syncthreads();

    // pass A (P and NT are multiples of 64, so each wave's i-range stays in one j)
    for (int i = tid; i < TC * P; i += NT) {
        int j = i / P;
        int p = i - j * P;
        int idx = (c0 + j) * P + p;
        float uu = u[idx] + 1e-10f;
        float g = -__logf(-__logf(uu) + 1e-10f);
        bool pres = (logits[idx] + g) > 0.0f;
        unsigned long long m = __ballot(pres);
        int base = 0;
        if (lane == 0) base = atomicAdd(&npres[j], (int)__popcll(m));
        base = __shfl(base, 0);
        if (pres) {
            int pos = __popcll(m & ((1ull << lane) - 1));
            plist[j * P + base + pos] = p;
        }
    }
    __syncthreads();

    const int j = tid >> 7;
    const int d = tid & (DD - 1);
    const int n = npres[j];
    const int n4 = n & ~3;
    const int* pl = &plist[j * P];

    // pass B: beta sums over present parents (weight exactly 1)
    float dmn_a = 0.f, dmn_b = 0.f, dmx_a = 0.f, dmx_b = 0.f;
    for (int k = 0; k < n4; k += 4) {
        int4 p4 = *(const int4*)(pl + k);
        float a0 = pb_min[p4.x * DD + d];
        float a1 = pb_min[p4.y * DD + d];
        float a2 = pb_min[p4.z * DD + d];
        float a3 = pb_min[p4.w * DD + d];
        float c0v = pb_max[p4.x * DD + d];
        float c1 = pb_max[p4.y * DD + d];
        float c2 = pb_max[p4.z * DD + d];
        float c3 = pb_max[p4.w * DD + d];
        dmn_a += a0 + a2; dmn_b += a1 + a3;
        dmx_a += c0v + c2; dmx_b += c1 + c3;
    }
    for (int k = n4; k < n; ++k) {
        int p = pl[k];
        dmn_a += pb_min[p * DD + d];
        dmx_a += pb_max[p * DD + d];
    }

    const float wsv = (float)n + 1e-10f;
    const float bmin = (dmn_a + dmn_b) / wsv;
    const float bmax = (dmx_a + dmx_b) / wsv;
    const float rmin = 1.0f / fmaxf(bmin, 1e-30f);
    const float nrmax = -1.0f / fmaxf(bmax, 1e-30f);
    const float Mmm = cm_min[d];
    const float Mng = cm_neg[d];
    const float negM1 = -rmin * Mmm;     // exp arg: mm*rmin - rmin*Mmm <= 0
    const float negM2 = nrmax * Mng;     // exp arg: mx*nrmax - (-nrmax)*... <= 0

    // pass C
    float s1a = 0.f, s1b = 0.f, s2a = 0.f, s2b = 0.f;
    for (int k = 0; k < n4; k += 4) {
        int4 p4 = *(const int4*)(pl + k);
        float m0 = pmu_min[p4.x * DD + d];
        float m1 = pmu_min[p4.y * DD + d];
        float m2 = pmu_min[p4.z * DD + d];
        float m3 = pmu_min[p4.w * DD + d];
        float x0 = pmu_max[p4.x * DD + d];
        float x1 = pmu_max[p4.y * DD + d];
        float x2 = pmu_max[p4.z * DD + d];
        float x3 = pmu_max[p4.w * DD + d];
        s1a += __expf(fmaf(m0, rmin, negM1));
        s1b += __expf(fmaf(m1, rmin, negM1));
        s1a += __expf(fmaf(m2, rmin, negM1));
        s1b += __expf(fmaf(m3, rmin, negM1));
        s2a += __expf(fmaf(x0, nrmax, negM2));
        s2b += __expf(fmaf(x1, nrmax, negM2));
        s2a += __expf(fmaf(x2, nrmax, negM2));
        s2b += __expf(fmaf(x3, nrmax, negM2));
    }
    for (int k = n4; k < n; ++k) {
        int p = pl[k];
        s1a += __expf(fmaf(pmu_min[p * DD + d], rmin, negM1));
        s2a += __expf(fmaf(pmu_max[p * DD + d], nrmax, negM2));
    }

    const float S1 = fmaxf(s1a + s1b, 1e-35f);
    const float S2 = fmaxf(s2a + s2b, 1e-35f);
    const int idx = (c0 + j) * DD + d;
    o_mu_min[idx] = bmin * fmaf(rmin, Mmm, __logf(S1));
    o_mu_max[idx] = -bmax * fmaf(-nrmax, Mng, __logf(S2));
    o_b_min[idx]  = bmin;
    o_b_max[idx]  = bmax;
}

extern "C" void kernel_launch(void* const* d_in, const int* in_sizes, int n_in,
                              void* d_out, int out_size, void* d_ws, size_t ws_size,
                              hipStream_t stream) {
    const float* mu_min0  = (const float*)d_in[0];
    const float* mu_max0  = (const float*)d_in[1];
    const float* braw_min = (const float*)d_in[2];
    const float* braw_max = (const float*)d_in[3];
    const float* adj0     = (const float*)d_in[4];   // (512, 64)
    const float* adj1     = (const float*)d_in[5];   // (2048, 512)
    const float* u0       = (const float*)d_in[6];   // (1, 512, 64)
    const float* u1       = (const float*)d_in[7];   // (1, 2048, 512)
    float* out = (float*)d_out;
    float* ws = (float*)d_ws;

    float* cm0_min = ws;
    float* cm0_neg = ws + 128;
    float* cm1_min = ws + 256;
    float* cm1_neg = ws + 384;

    // out offsets (f32): 0:mu_min0 8192:mu_max0 16384:bmin0 24576:bmax0
    // 32768:mu_min1 98304:mu_max1 163840:b_min1 229376:b_max1 (each 65536)
    // 294912:mu_min2 557056:mu_max2 819200:b_min2 1081344:b_max2 (each 262144)

    k_root<<<dim3(32), dim3(256), 0, stream>>>(mu_min0, mu_max0, braw_min, braw_max, out);

    k_prep<64><<<dim3(2), dim3(1024), 0, stream>>>(mu_min0, mu_max0, cm0_min, cm0_neg);

    k_levelc<64, 2, 256><<<dim3(256), dim3(256), 0, stream>>>(
        adj0, u0, out + 16384, out + 24576, mu_min0, mu_max0, cm0_min, cm0_neg,
        out + 32768, out + 98304, out + 163840, out + 229376);

    k_prep<512><<<dim3(2), dim3(1024), 0, stream>>>(out + 32768, out + 98304, cm1_min, cm1_neg);

    k_levelc<512, 4, 512><<<dim3(512), dim3(512), 0, stream>>>(
        adj1, u1, out + 163840, out + 229376, out + 32768, out + 98304, cm1_min, cm1_neg,
        out + 294912, out + 557056, out + 819200, out + 1081344);
}